// Round 1
// baseline (247.312 us; speedup 1.0000x reference)
//
#include <hip/hip_runtime.h>
#include <hip/hip_bf16.h>

#define S_LEN 2048
#define HEADS 16
#define DIM 64
#define QBLK 64
#define KVBLK 64

typedef __attribute__((ext_vector_type(8))) short short8;
typedef __attribute__((ext_vector_type(4))) float f32x4;

__device__ __forceinline__ short f2bf(float f) {
    __hip_bfloat16 h = __float2bfloat16(f);
    return *reinterpret_cast<const short*>(&h);
}

// LDS layout (bytes):
//  Kl : [64][64] bf16 row-major, 128B/row, swizzle byte^=((row&7)<<4)   (8 KiB)
//  Vl : [64 d][64 kv] bf16 (V transposed), same swizzle                 (8 KiB)
//  Pl : per-wave [16][72] bf16, 144B/row (stride-skew, no swizzle)      (9 KiB)
__global__ __launch_bounds__(256)
void fa_fwd_kernel(const float* __restrict__ q_q, const float* __restrict__ k_q,
                   const float* __restrict__ v_q, const float* __restrict__ q_scale,
                   const float* __restrict__ k_scale, const float* __restrict__ v_scale,
                   float* __restrict__ out)
{
    __shared__ char lds[8192 + 8192 + 4 * 16 * 144];
    char* Kl = lds;
    char* Vl = lds + 8192;
    char* Pl = lds + 16384;

    const int tid = threadIdx.x;
    const int w   = tid >> 6;
    const int l   = tid & 63;
    const int l15 = l & 15;
    const int l4  = l >> 4;

    // heavy q-tiles first for tail balance
    const int qtile = (int)gridDim.x - 1 - (int)blockIdx.x;
    const int bh = blockIdx.y;
    const int b  = bh >> 4;   // / HEADS
    const int h  = bh & 15;   // % HEADS

    const int qbase = qtile * QBLK;
    const int sstride = HEADS * DIM; // 1024 floats between seq positions
    const size_t bh_off = ((size_t)b * S_LEN * HEADS + h) * DIM;

    const float c2 = q_scale[h] * k_scale[h] * 0.125f * 1.4426950408889634f; // /sqrt(64) * log2(e)
    const float vs = v_scale[h];

    // ---- Q fragments (held in registers for the whole kv loop) ----
    // A-frag layout: row = l&15 (q-local), k = (l>>4)*8 + j  (+32 per k-chunk)
    short8 qf[2];
    const int w_qmin = qbase + w * 16;
    {
        const float* qp = q_q + bh_off + (size_t)(w_qmin + l15) * sstride;
        #pragma unroll
        for (int kc = 0; kc < 2; ++kc) {
            const int d0 = kc * 32 + l4 * 8;
            float4 a = *reinterpret_cast<const float4*>(qp + d0);
            float4 c = *reinterpret_cast<const float4*>(qp + d0 + 4);
            short8 f;
            f[0] = f2bf(a.x); f[1] = f2bf(a.y); f[2] = f2bf(a.z); f[3] = f2bf(a.w);
            f[4] = f2bf(c.x); f[5] = f2bf(c.y); f[6] = f2bf(c.z); f[7] = f2bf(c.w);
            qf[kc] = f;
        }
    }

    f32x4 O[4] = {{0.f,0.f,0.f,0.f},{0.f,0.f,0.f,0.f},{0.f,0.f,0.f,0.f},{0.f,0.f,0.f,0.f}};
    float m2[4], lsum[4];
    #pragma unroll
    for (int r = 0; r < 4; ++r) { m2[r] = -1e30f; lsum[r] = 0.f; }

    const int kv_end = qbase + QBLK;

    for (int kvbase = 0; kvbase < kv_end; kvbase += KVBLK) {
        __syncthreads(); // previous tile's LDS reads complete before overwrite

        // ---- stage K tile: [kv][d] bf16, swizzled ----
        {
            const float* kp = k_q + bh_off + (size_t)kvbase * sstride;
            #pragma unroll
            for (int i = 0; i < 4; ++i) {
                const int f4i = tid + i * 256;
                const int row  = f4i >> 4;
                const int col4 = (f4i & 15) * 4;
                float4 v = *reinterpret_cast<const float4*>(kp + (size_t)row * sstride + col4);
                uint2 pk;
                pk.x = (unsigned)(unsigned short)f2bf(v.x) | ((unsigned)(unsigned short)f2bf(v.y) << 16);
                pk.y = (unsigned)(unsigned short)f2bf(v.z) | ((unsigned)(unsigned short)f2bf(v.w) << 16);
                const int byte = row * 128 + ((col4 * 2) ^ ((row & 7) << 4));
                *reinterpret_cast<uint2*>(&Kl[byte]) = pk;
            }
        }
        // ---- stage V tile transposed: Vt[d][kv] bf16, swizzled ----
        {
            const float* vp = v_q + bh_off + (size_t)kvbase * sstride;
            #pragma unroll
            for (int g = 0; g < 2; ++g) {
                const int kv0 = w * 16 + g * 8;
                short8 f;
                #pragma unroll
                for (int j = 0; j < 8; ++j)
                    f[j] = f2bf(vp[(size_t)(kv0 + j) * sstride + l]);
                const int byte = l * 128 + ((kv0 * 2) ^ ((l & 7) << 4));
                *reinterpret_cast<short8*>(&Vl[byte]) = f;
            }
        }
        __syncthreads();

        if (kvbase <= w_qmin + 15) {              // wave has at least one unmasked row
            const bool needMask = (kvbase + KVBLK - 1 > w_qmin);

            // ---- QK^T: S[q][kv], 4 col-blocks x 2 k-chunks ----
            f32x4 sc[4];
            #pragma unroll
            for (int cb = 0; cb < 4; ++cb) {
                f32x4 acc = {0.f, 0.f, 0.f, 0.f};
                #pragma unroll
                for (int kc = 0; kc < 2; ++kc) {
                    const int row  = cb * 16 + l15;
                    const int colb = (kc * 32 + l4 * 8) * 2;
                    short8 bf = *reinterpret_cast<const short8*>(
                        &Kl[row * 128 + (colb ^ ((row & 7) << 4))]);
                    acc = __builtin_amdgcn_mfma_f32_16x16x32_bf16(qf[kc], bf, acc, 0, 0, 0);
                }
                sc[cb] = acc;
            }

            // ---- online softmax (base-2) ----
            float p[4][4]; // [cb][r]
            #pragma unroll
            for (int cb = 0; cb < 4; ++cb) {
                const int kv = kvbase + cb * 16 + l15;
                #pragma unroll
                for (int r = 0; r < 4; ++r) {
                    float s = sc[cb][r] * c2;
                    if (needMask && kv > (w_qmin + l4 * 4 + r)) s = -1e30f;
                    p[cb][r] = s;
                }
            }
            char* Pw = Pl + w * (16 * 144);
            #pragma unroll
            for (int r = 0; r < 4; ++r) {
                float t = fmaxf(fmaxf(p[0][r], p[1][r]), fmaxf(p[2][r], p[3][r]));
                t = fmaxf(t, __shfl_xor(t, 1));
                t = fmaxf(t, __shfl_xor(t, 2));
                t = fmaxf(t, __shfl_xor(t, 4));
                t = fmaxf(t, __shfl_xor(t, 8));
                const float mn   = fmaxf(m2[r], t);
                const float corr = exp2f(m2[r] - mn);
                m2[r] = mn;
                lsum[r] *= corr;
                #pragma unroll
                for (int db = 0; db < 4; ++db) O[db][r] *= corr;
                float ps = 0.f;
                #pragma unroll
                for (int cb = 0; cb < 4; ++cb) {
                    const float e = exp2f(p[cb][r] - mn);
                    p[cb][r] = e;
                    ps += e;
                }
                lsum[r] += ps;
                // write P row to per-wave LDS (C-layout -> A-layout reshape)
                const int prow = l4 * 4 + r;
                #pragma unroll
                for (int cb = 0; cb < 4; ++cb)
                    *reinterpret_cast<short*>(&Pw[prow * 144 + (cb * 16 + l15) * 2]) =
                        f2bf(p[cb][r]);
            }

            // ---- PV: O += P * V ----
            #pragma unroll
            for (int kc = 0; kc < 2; ++kc) {
                short8 pf = *reinterpret_cast<const short8*>(
                    &Pw[l15 * 144 + (kc * 32 + l4 * 8) * 2]);
                #pragma unroll
                for (int db = 0; db < 4; ++db) {
                    const int row  = db * 16 + l15;
                    const int colb = (kc * 32 + l4 * 8) * 2;
                    short8 vf = *reinterpret_cast<const short8*>(
                        &Vl[row * 128 + (colb ^ ((row & 7) << 4))]);
                    O[db] = __builtin_amdgcn_mfma_f32_16x16x32_bf16(pf, vf, O[db], 0, 0, 0);
                }
            }
        }
    }

    // ---- epilogue: normalize, apply v_scale, store fp32 ----
    #pragma unroll
    for (int r = 0; r < 4; ++r) {
        float t = lsum[r];
        t += __shfl_xor(t, 1);
        t += __shfl_xor(t, 2);
        t += __shfl_xor(t, 4);
        t += __shfl_xor(t, 8);
        const float inv = vs / t;
        const int q = w_qmin + l4 * 4 + r;
        float* op = out + bh_off + (size_t)q * sstride;
        #pragma unroll
        for (int db = 0; db < 4; ++db)
            op[db * 16 + l15] = O[db][r] * inv;
    }
}

extern "C" void kernel_launch(void* const* d_in, const int* in_sizes, int n_in,
                              void* d_out, int out_size, void* d_ws, size_t ws_size,
                              hipStream_t stream) {
    const float* q_q     = (const float*)d_in[0];
    const float* k_q     = (const float*)d_in[1];
    const float* v_q     = (const float*)d_in[2];
    const float* q_scale = (const float*)d_in[3];
    const float* k_scale = (const float*)d_in[4];
    const float* v_scale = (const float*)d_in[5];
    float* out = (float*)d_out;

    const int B = 4;
    dim3 grid(S_LEN / QBLK, B * HEADS);
    dim3 block(256);
    fa_fwd_kernel<<<grid, block, 0, stream>>>(q_q, k_q, v_q, q_scale, k_scale, v_scale, out);
}

// Round 2
// 225.234 us; speedup vs baseline: 1.0980x; 1.0980x over previous
//
#include <hip/hip_runtime.h>
#include <hip/hip_bf16.h>

#define S_LEN 2048
#define HEADS 16
#define DIM 64
#define QBLK 64
#define KVBLK 64
#define NBH 64          // B*H
#define NTILES 32       // S_LEN / KVBLK

typedef __attribute__((ext_vector_type(8))) short short8;
typedef __attribute__((ext_vector_type(4))) float f32x4;

__device__ __forceinline__ short f2bf(float f) {
    __hip_bfloat16 h = __float2bfloat16(f);
    return *reinterpret_cast<const short*>(&h);
}

__device__ __forceinline__ void gl_lds16(const void* g, void* s) {
    __builtin_amdgcn_global_load_lds(
        (const __attribute__((address_space(1))) unsigned*)g,
        (__attribute__((address_space(3))) unsigned*)s, 16, 0, 0);
}

// ---------------- prepass: K -> bf16, swizzled LDS image ----------------
// Kg layout: [bh][kv] rows of 128B, byte-in-row = (d*2) ^ ((kv&7)<<4)
__global__ __launch_bounds__(256)
void prep_k_kernel(const float* __restrict__ k_q, char* __restrict__ Kg)
{
    const int u  = blockIdx.x * 256 + threadIdx.x;   // 1,048,576 units
    const int c  = u & 7;                            // 16B chunk in row
    const int kv = (u >> 3) & (S_LEN - 1);
    const int bh = u >> 14;
    const int b  = bh >> 4;
    const int h  = bh & 15;

    const float* src = k_q + ((size_t)b * S_LEN + kv) * (HEADS * DIM) + h * DIM + c * 8;
    float4 a = *reinterpret_cast<const float4*>(src);
    float4 d = *reinterpret_cast<const float4*>(src + 4);
    short8 f;
    f[0]=f2bf(a.x); f[1]=f2bf(a.y); f[2]=f2bf(a.z); f[3]=f2bf(a.w);
    f[4]=f2bf(d.x); f[5]=f2bf(d.y); f[6]=f2bf(d.z); f[7]=f2bf(d.w);
    char* dst = Kg + ((size_t)bh * S_LEN + kv) * 128 + ((c * 16) ^ ((kv & 7) << 4));
    *reinterpret_cast<short8*>(dst) = f;
}

// ---------------- prepass: V -> bf16 transposed, swizzled -----------------
// Vg layout: [bh][tile][d] rows of 128B (kv in row), byte = (kv*2) ^ ((d&7)<<4)
__global__ __launch_bounds__(256)
void prep_v_kernel(const float* __restrict__ v_q, char* __restrict__ Vg)
{
    __shared__ short Vt[64][72];
    const int tid  = threadIdx.x;
    const int tile = blockIdx.x;
    const int bh   = blockIdx.y;
    const int b    = bh >> 4;
    const int h    = bh & 15;
    const int kvbase = tile * KVBLK;

    // load [kv][d] fp32, convert, transpose into LDS
    {
        const int kv = tid >> 2;
        const int d0 = (tid & 3) * 16;
        const float* src = v_q + ((size_t)b * S_LEN + kvbase + kv) * (HEADS * DIM) + h * DIM + d0;
        #pragma unroll
        for (int g = 0; g < 4; ++g) {
            float4 v = *reinterpret_cast<const float4*>(src + g * 4);
            Vt[d0 + g * 4 + 0][kv] = f2bf(v.x);
            Vt[d0 + g * 4 + 1][kv] = f2bf(v.y);
            Vt[d0 + g * 4 + 2][kv] = f2bf(v.z);
            Vt[d0 + g * 4 + 3][kv] = f2bf(v.w);
        }
    }
    __syncthreads();
    // write out rows of Vt with swizzle
    {
        const int d = tid >> 2;
        const int c = tid & 3;                       // two 16B chunks per thread
        short8 f0 = *reinterpret_cast<const short8*>(&Vt[d][c * 16]);
        short8 f1 = *reinterpret_cast<const short8*>(&Vt[d][c * 16 + 8]);
        char* base = Vg + (((size_t)bh * NTILES + tile) * 64 + d) * 128;
        const int s = (d & 7) << 4;
        *reinterpret_cast<short8*>(base + ((c * 32) ^ s))      = f0;
        *reinterpret_cast<short8*>(base + ((c * 32 + 16) ^ s)) = f1;
    }
}

// ---------------- main attention (bf16 K/V pre-staged in d_ws) ------------
__global__ __launch_bounds__(256)
void fa_fwd_pre(const float* __restrict__ q_q, const char* __restrict__ Kg,
                const char* __restrict__ Vg, const float* __restrict__ q_scale,
                const float* __restrict__ k_scale, const float* __restrict__ v_scale,
                float* __restrict__ out)
{
    __shared__ __attribute__((aligned(16))) char Kl[2][8192];
    __shared__ __attribute__((aligned(16))) char Vl[2][8192];
    __shared__ __attribute__((aligned(16))) char Pl[4 * 16 * 144];

    const int tid = threadIdx.x;
    const int w   = tid >> 6;
    const int l   = tid & 63;
    const int l15 = l & 15;
    const int l4  = l >> 4;

    const int qtile = (int)gridDim.x - 1 - (int)blockIdx.x;  // heavy first
    const int bh = blockIdx.y;
    const int b  = bh >> 4;
    const int h  = bh & 15;

    const int qbase = qtile * QBLK;
    const int sstride = HEADS * DIM;
    const size_t bh_off = ((size_t)b * S_LEN * HEADS + h) * DIM;

    const float c2 = q_scale[h] * k_scale[h] * 0.125f * 1.4426950408889634f;
    const float vs = v_scale[h];

    // Q fragments, scale folded in. A-frag: row=l15, k=(l>>4)*8+j (+32/chunk)
    short8 qf[2];
    const int w_qmin = qbase + w * 16;
    {
        const float* qp = q_q + bh_off + (size_t)(w_qmin + l15) * sstride;
        #pragma unroll
        for (int kc = 0; kc < 2; ++kc) {
            const int d0 = kc * 32 + l4 * 8;
            float4 a = *reinterpret_cast<const float4*>(qp + d0);
            float4 c = *reinterpret_cast<const float4*>(qp + d0 + 4);
            short8 f;
            f[0]=f2bf(a.x*c2); f[1]=f2bf(a.y*c2); f[2]=f2bf(a.z*c2); f[3]=f2bf(a.w*c2);
            f[4]=f2bf(c.x*c2); f[5]=f2bf(c.y*c2); f[6]=f2bf(c.z*c2); f[7]=f2bf(c.w*c2);
            qf[kc] = f;
        }
    }

    f32x4 O[4] = {{0.f,0.f,0.f,0.f},{0.f,0.f,0.f,0.f},{0.f,0.f,0.f,0.f},{0.f,0.f,0.f,0.f}};
    float m2[4], lsum[4];
    #pragma unroll
    for (int r = 0; r < 4; ++r) { m2[r] = -1e30f; lsum[r] = 0.f; }

    const int ntiles = qtile + 1;
    const size_t kg_bh = (size_t)bh * S_LEN * 128;
    const size_t vg_bh = (size_t)bh * NTILES * 8192;
    const int woff = w * 2048 + l * 16;

    // stage one tile (per-wave slice) into buffer X
    auto STAGE = [&](int X, int t) {
        const char* ks = Kg + kg_bh + (size_t)t * KVBLK * 128 + woff;
        const char* vsrc = Vg + vg_bh + (size_t)t * 8192 + woff;
        gl_lds16(ks,          &Kl[X][w * 2048]);
        gl_lds16(ks + 1024,   &Kl[X][w * 2048 + 1024]);
        gl_lds16(vsrc,        &Vl[X][w * 2048]);
        gl_lds16(vsrc + 1024, &Vl[X][w * 2048 + 1024]);
    };

    STAGE(0, 0);
    char* Pw = Pl + w * (16 * 144);

    for (int t = 0; t < ntiles; ++t) {
        const int cur = t & 1;
        if (t + 1 < ntiles) {
            STAGE(cur ^ 1, t + 1);
            asm volatile("s_waitcnt vmcnt(4)" ::: "memory");
        } else {
            asm volatile("s_waitcnt vmcnt(0)" ::: "memory");
        }
        __builtin_amdgcn_s_barrier();

        const int kvbase = t * KVBLK;
        const bool needMask = (t == ntiles - 1);

        // ---- QK^T ----
        f32x4 sc[4];
        #pragma unroll
        for (int cb = 0; cb < 4; ++cb) {
            f32x4 acc = {0.f, 0.f, 0.f, 0.f};
            #pragma unroll
            for (int kc = 0; kc < 2; ++kc) {
                const int row  = cb * 16 + l15;
                const int colb = (kc * 32 + l4 * 8) * 2;
                short8 bf = *reinterpret_cast<const short8*>(
                    &Kl[cur][row * 128 + (colb ^ ((row & 7) << 4))]);
                acc = __builtin_amdgcn_mfma_f32_16x16x32_bf16(qf[kc], bf, acc, 0, 0, 0);
            }
            sc[cb] = acc;
        }

        // ---- online softmax (base-2; scale pre-folded into Q) ----
        float p[4][4];
        #pragma unroll
        for (int cb = 0; cb < 4; ++cb) {
            const int kv = kvbase + cb * 16 + l15;
            #pragma unroll
            for (int r = 0; r < 4; ++r) {
                float s = sc[cb][r];
                if (needMask && kv > (w_qmin + l4 * 4 + r)) s = -1e30f;
                p[cb][r] = s;
            }
        }
        #pragma unroll
        for (int r = 0; r < 4; ++r) {
            float tmx = fmaxf(fmaxf(p[0][r], p[1][r]), fmaxf(p[2][r], p[3][r]));
            tmx = fmaxf(tmx, __shfl_xor(tmx, 1));
            tmx = fmaxf(tmx, __shfl_xor(tmx, 2));
            tmx = fmaxf(tmx, __shfl_xor(tmx, 4));
            tmx = fmaxf(tmx, __shfl_xor(tmx, 8));
            const float mn   = fmaxf(m2[r], tmx);
            const float corr = exp2f(m2[r] - mn);
            m2[r] = mn;
            lsum[r] *= corr;
            #pragma unroll
            for (int db = 0; db < 4; ++db) O[db][r] *= corr;
            float ps = 0.f;
            #pragma unroll
            for (int cb = 0; cb < 4; ++cb) {
                const float e = exp2f(p[cb][r] - mn);
                p[cb][r] = e;
                ps += e;
            }
            lsum[r] += ps;
            const int prow = l4 * 4 + r;
            #pragma unroll
            for (int cb = 0; cb < 4; ++cb)
                *reinterpret_cast<short*>(&Pw[prow * 144 + (cb * 16 + l15) * 2]) =
                    f2bf(p[cb][r]);
        }

        // ---- PV ----
        #pragma unroll
        for (int kc = 0; kc < 2; ++kc) {
            short8 pf = *reinterpret_cast<const short8*>(
                &Pw[l15 * 144 + (kc * 32 + l4 * 8) * 2]);
            #pragma unroll
            for (int db = 0; db < 4; ++db) {
                const int row  = db * 16 + l15;
                const int colb = (kc * 32 + l4 * 8) * 2;
                short8 vf = *reinterpret_cast<const short8*>(
                    &Vl[cur][row * 128 + (colb ^ ((row & 7) << 4))]);
                O[db] = __builtin_amdgcn_mfma_f32_16x16x32_bf16(pf, vf, O[db], 0, 0, 0);
            }
        }

        asm volatile("s_waitcnt lgkmcnt(0)" ::: "memory");
        __builtin_amdgcn_s_barrier();
    }

    // ---- epilogue ----
    #pragma unroll
    for (int r = 0; r < 4; ++r) {
        float t = lsum[r];
        t += __shfl_xor(t, 1);
        t += __shfl_xor(t, 2);
        t += __shfl_xor(t, 4);
        t += __shfl_xor(t, 8);
        const float inv = vs / t;
        const int q = w_qmin + l4 * 4 + r;
        float* op = out + bh_off + (size_t)q * sstride;
        #pragma unroll
        for (int db = 0; db < 4; ++db)
            op[db * 16 + l15] = O[db][r] * inv;
    }
}

// ---------------- fallback (round-1 kernel, used if ws too small) ---------
__global__ __launch_bounds__(256)
void fa_fwd_fallback(const float* __restrict__ q_q, const float* __restrict__ k_q,
                     const float* __restrict__ v_q, const float* __restrict__ q_scale,
                     const float* __restrict__ k_scale, const float* __restrict__ v_scale,
                     float* __restrict__ out)
{
    __shared__ char lds[8192 + 8192 + 4 * 16 * 144];
    char* Kl = lds;
    char* Vl = lds + 8192;
    char* Pl = lds + 16384;

    const int tid = threadIdx.x;
    const int w   = tid >> 6;
    const int l   = tid & 63;
    const int l15 = l & 15;
    const int l4  = l >> 4;

    const int qtile = (int)gridDim.x - 1 - (int)blockIdx.x;
    const int bh = blockIdx.y;
    const int b  = bh >> 4;
    const int h  = bh & 15;

    const int qbase = qtile * QBLK;
    const int sstride = HEADS * DIM;
    const size_t bh_off = ((size_t)b * S_LEN * HEADS + h) * DIM;

    const float c2 = q_scale[h] * k_scale[h] * 0.125f * 1.4426950408889634f;
    const float vs = v_scale[h];

    short8 qf[2];
    const int w_qmin = qbase + w * 16;
    {
        const float* qp = q_q + bh_off + (size_t)(w_qmin + l15) * sstride;
        #pragma unroll
        for (int kc = 0; kc < 2; ++kc) {
            const int d0 = kc * 32 + l4 * 8;
            float4 a = *reinterpret_cast<const float4*>(qp + d0);
            float4 c = *reinterpret_cast<const float4*>(qp + d0 + 4);
            short8 f;
            f[0]=f2bf(a.x*c2); f[1]=f2bf(a.y*c2); f[2]=f2bf(a.z*c2); f[3]=f2bf(a.w*c2);
            f[4]=f2bf(c.x*c2); f[5]=f2bf(c.y*c2); f[6]=f2bf(c.z*c2); f[7]=f2bf(c.w*c2);
            qf[kc] = f;
        }
    }

    f32x4 O[4] = {{0.f,0.f,0.f,0.f},{0.f,0.f,0.f,0.f},{0.f,0.f,0.f,0.f},{0.f,0.f,0.f,0.f}};
    float m2[4], lsum[4];
    #pragma unroll
    for (int r = 0; r < 4; ++r) { m2[r] = -1e30f; lsum[r] = 0.f; }

    const int kv_end = qbase + QBLK;

    for (int kvbase = 0; kvbase < kv_end; kvbase += KVBLK) {
        __syncthreads();
        {
            const float* kp = k_q + bh_off + (size_t)kvbase * sstride;
            #pragma unroll
            for (int i = 0; i < 4; ++i) {
                const int f4i = tid + i * 256;
                const int row  = f4i >> 4;
                const int col4 = (f4i & 15) * 4;
                float4 v = *reinterpret_cast<const float4*>(kp + (size_t)row * sstride + col4);
                uint2 pk;
                pk.x = (unsigned)(unsigned short)f2bf(v.x) | ((unsigned)(unsigned short)f2bf(v.y) << 16);
                pk.y = (unsigned)(unsigned short)f2bf(v.z) | ((unsigned)(unsigned short)f2bf(v.w) << 16);
                const int byte = row * 128 + ((col4 * 2) ^ ((row & 7) << 4));
                *reinterpret_cast<uint2*>(&Kl[byte]) = pk;
            }
        }
        {
            const float* vp = v_q + bh_off + (size_t)kvbase * sstride;
            #pragma unroll
            for (int g = 0; g < 2; ++g) {
                const int kv0 = w * 16 + g * 8;
                short8 f;
                #pragma unroll
                for (int j = 0; j < 8; ++j)
                    f[j] = f2bf(vp[(size_t)(kv0 + j) * sstride + l]);
                const int byte = l * 128 + ((kv0 * 2) ^ ((l & 7) << 4));
                *reinterpret_cast<short8*>(&Vl[byte]) = f;
            }
        }
        __syncthreads();

        const bool needMask = (kvbase + KVBLK - 1 > w_qmin);
        f32x4 sc[4];
        #pragma unroll
        for (int cb = 0; cb < 4; ++cb) {
            f32x4 acc = {0.f, 0.f, 0.f, 0.f};
            #pragma unroll
            for (int kc = 0; kc < 2; ++kc) {
                const int row  = cb * 16 + l15;
                const int colb = (kc * 32 + l4 * 8) * 2;
                short8 bf = *reinterpret_cast<const short8*>(
                    &Kl[row * 128 + (colb ^ ((row & 7) << 4))]);
                acc = __builtin_amdgcn_mfma_f32_16x16x32_bf16(qf[kc], bf, acc, 0, 0, 0);
            }
            sc[cb] = acc;
        }
        float p[4][4];
        #pragma unroll
        for (int cb = 0; cb < 4; ++cb) {
            const int kv = kvbase + cb * 16 + l15;
            #pragma unroll
            for (int r = 0; r < 4; ++r) {
                float s = sc[cb][r];
                if (needMask && kv > (w_qmin + l4 * 4 + r)) s = -1e30f;
                p[cb][r] = s;
            }
        }
        char* Pw = Pl + w * (16 * 144);
        #pragma unroll
        for (int r = 0; r < 4; ++r) {
            float t = fmaxf(fmaxf(p[0][r], p[1][r]), fmaxf(p[2][r], p[3][r]));
            t = fmaxf(t, __shfl_xor(t, 1));
            t = fmaxf(t, __shfl_xor(t, 2));
            t = fmaxf(t, __shfl_xor(t, 4));
            t = fmaxf(t, __shfl_xor(t, 8));
            const float mn   = fmaxf(m2[r], t);
            const float corr = exp2f(m2[r] - mn);
            m2[r] = mn;
            lsum[r] *= corr;
            #pragma unroll
            for (int db = 0; db < 4; ++db) O[db][r] *= corr;
            float ps = 0.f;
            #pragma unroll
            for (int cb = 0; cb < 4; ++cb) {
                const float e = exp2f(p[cb][r] - mn);
                p[cb][r] = e;
                ps += e;
            }
            lsum[r] += ps;
            const int prow = l4 * 4 + r;
            #pragma unroll
            for (int cb = 0; cb < 4; ++cb)
                *reinterpret_cast<short*>(&Pw[prow * 144 + (cb * 16 + l15) * 2]) =
                    f2bf(p[cb][r]);
        }
        #pragma unroll
        for (int kc = 0; kc < 2; ++kc) {
            short8 pf = *reinterpret_cast<const short8*>(
                &Pw[l15 * 144 + (kc * 32 + l4 * 8) * 2]);
            #pragma unroll
            for (int db = 0; db < 4; ++db) {
                const int row  = db * 16 + l15;
                const int colb = (kc * 32 + l4 * 8) * 2;
                short8 vf = *reinterpret_cast<const short8*>(
                    &Vl[row * 128 + (colb ^ ((row & 7) << 4))]);
                O[db] = __builtin_amdgcn_mfma_f32_16x16x32_bf16(pf, vf, O[db], 0, 0, 0);
            }
        }
    }

    #pragma unroll
    for (int r = 0; r < 4; ++r) {
        float t = lsum[r];
        t += __shfl_xor(t, 1);
        t += __shfl_xor(t, 2);
        t += __shfl_xor(t, 4);
        t += __shfl_xor(t, 8);
        const float inv = vs / t;
        const int q = w_qmin + l4 * 4 + r;
        float* op = out + bh_off + (size_t)q * sstride;
        #pragma unroll
        for (int db = 0; db < 4; ++db)
            op[db * 16 + l15] = O[db][r] * inv;
    }
}

extern "C" void kernel_launch(void* const* d_in, const int* in_sizes, int n_in,
                              void* d_out, int out_size, void* d_ws, size_t ws_size,
                              hipStream_t stream) {
    const float* q_q     = (const float*)d_in[0];
    const float* k_q     = (const float*)d_in[1];
    const float* v_q     = (const float*)d_in[2];
    const float* q_scale = (const float*)d_in[3];
    const float* k_scale = (const float*)d_in[4];
    const float* v_scale = (const float*)d_in[5];
    float* out = (float*)d_out;

    const size_t kbytes = (size_t)NBH * S_LEN * 128;   // 16.78 MB
    const size_t need   = kbytes * 2;

    if (ws_size >= need) {
        char* Kg = (char*)d_ws;
        char* Vg = Kg + kbytes;
        prep_k_kernel<<<dim3(4096), dim3(256), 0, stream>>>(k_q, Kg);
        prep_v_kernel<<<dim3(NTILES, NBH), dim3(256), 0, stream>>>(v_q, Vg);
        fa_fwd_pre<<<dim3(NTILES, NBH), dim3(256), 0, stream>>>(
            q_q, Kg, Vg, q_scale, k_scale, v_scale, out);
    } else {
        fa_fwd_fallback<<<dim3(NTILES, NBH), dim3(256), 0, stream>>>(
            q_q, k_q, v_q, q_scale, k_scale, v_scale, out);
    }
}

// Round 3
// 145.458 us; speedup vs baseline: 1.7002x; 1.5484x over previous
//
#include <hip/hip_runtime.h>
#include <hip/hip_bf16.h>

#define S_LEN 2048
#define HEADS 16
#define DIM 64
#define QBLK 64
#define KVBLK 64
#define NBH 64          // B*H
#define NTILES 32       // S_LEN / KVBLK
#define MBIAS 9.0f      // static log2-domain max bound (softmax shift-invariant)

typedef __attribute__((ext_vector_type(8))) short short8;
typedef __attribute__((ext_vector_type(4))) short short4v;
typedef __attribute__((ext_vector_type(4))) float f32x4;

__device__ __forceinline__ short f2bf(float f) {
    __hip_bfloat16 h = __float2bfloat16(f);
    return *reinterpret_cast<const short*>(&h);
}

__device__ __forceinline__ void gl_lds16(const void* g, void* s) {
    __builtin_amdgcn_global_load_lds(
        (const __attribute__((address_space(1))) unsigned*)g,
        (__attribute__((address_space(3))) unsigned*)s, 16, 0, 0);
}

// ---------------- prepass: K -> bf16, swizzled LDS image ----------------
// Kg layout: [bh][kv] rows of 128B, byte-in-row = (d*2) ^ ((kv&7)<<4)
__global__ __launch_bounds__(256)
void prep_k_kernel(const float* __restrict__ k_q, char* __restrict__ Kg)
{
    const int u  = blockIdx.x * 256 + threadIdx.x;
    const int c  = u & 7;
    const int kv = (u >> 3) & (S_LEN - 1);
    const int bh = u >> 14;
    const int b  = bh >> 4;
    const int h  = bh & 15;

    const float* src = k_q + ((size_t)b * S_LEN + kv) * (HEADS * DIM) + h * DIM + c * 8;
    float4 a = *reinterpret_cast<const float4*>(src);
    float4 d = *reinterpret_cast<const float4*>(src + 4);
    short8 f;
    f[0]=f2bf(a.x); f[1]=f2bf(a.y); f[2]=f2bf(a.z); f[3]=f2bf(a.w);
    f[4]=f2bf(d.x); f[5]=f2bf(d.y); f[6]=f2bf(d.z); f[7]=f2bf(d.w);
    char* dst = Kg + ((size_t)bh * S_LEN + kv) * 128 + ((c * 16) ^ ((kv & 7) << 4));
    *reinterpret_cast<short8*>(dst) = f;
}

// ---------------- prepass: V -> bf16 transposed, swizzled -----------------
// Vg layout: [bh][tile][d] rows of 128B (kv in row), byte = (kv*2) ^ ((d&7)<<4)
__global__ __launch_bounds__(256)
void prep_v_kernel(const float* __restrict__ v_q, char* __restrict__ Vg)
{
    __shared__ short Vt[64][72];
    const int tid  = threadIdx.x;
    const int tile = blockIdx.x;
    const int bh   = blockIdx.y;
    const int b    = bh >> 4;
    const int h    = bh & 15;
    const int kvbase = tile * KVBLK;

    {
        const int kv = tid >> 2;
        const int d0 = (tid & 3) * 16;
        const float* src = v_q + ((size_t)b * S_LEN + kvbase + kv) * (HEADS * DIM) + h * DIM + d0;
        #pragma unroll
        for (int g = 0; g < 4; ++g) {
            float4 v = *reinterpret_cast<const float4*>(src + g * 4);
            Vt[d0 + g * 4 + 0][kv] = f2bf(v.x);
            Vt[d0 + g * 4 + 1][kv] = f2bf(v.y);
            Vt[d0 + g * 4 + 2][kv] = f2bf(v.z);
            Vt[d0 + g * 4 + 3][kv] = f2bf(v.w);
        }
    }
    __syncthreads();
    {
        const int d = tid >> 2;
        const int c = tid & 3;
        short8 f0 = *reinterpret_cast<const short8*>(&Vt[d][c * 16]);
        short8 f1 = *reinterpret_cast<const short8*>(&Vt[d][c * 16 + 8]);
        char* base = Vg + (((size_t)bh * NTILES + tile) * 64 + d) * 128;
        const int s = (d & 7) << 4;
        *reinterpret_cast<short8*>(base + ((c * 32) ^ s))      = f0;
        *reinterpret_cast<short8*>(base + ((c * 32 + 16) ^ s)) = f1;
    }
}

// ---------------- main attention: swapped-operand, static-max softmax -----
__global__ __launch_bounds__(256)
void fa_fwd_pre(const float* __restrict__ q_q, const char* __restrict__ Kg,
                const char* __restrict__ Vg, const float* __restrict__ q_scale,
                const float* __restrict__ k_scale, const float* __restrict__ v_scale,
                float* __restrict__ out)
{
    __shared__ __attribute__((aligned(16))) char Kl[2][8192];
    __shared__ __attribute__((aligned(16))) char Vl[2][8192];
    __shared__ __attribute__((aligned(16))) char Pl[8192];   // per-wave [16 q][64 kv] bf16, 128B rows

    const int tid = threadIdx.x;
    const int w   = tid >> 6;
    const int l   = tid & 63;
    const int l15 = l & 15;
    const int l4  = l >> 4;

    const int qtile = (int)gridDim.x - 1 - (int)blockIdx.x;  // heavy first
    const int bh = blockIdx.y;
    const int b  = bh >> 4;
    const int h  = bh & 15;

    const int qbase = qtile * QBLK;
    const int sstride = HEADS * DIM;
    const size_t bh_off = ((size_t)b * S_LEN * HEADS + h) * DIM;

    const float c2 = q_scale[h] * k_scale[h] * 0.125f * 1.4426950408889634f;
    const float vs = v_scale[h];

    // Q fragments, scale folded in. Used as MFMA B-operand: col=l15, k=l4*8+j (+32/kc)
    short8 qf[2];
    const int w_qmin = qbase + w * 16;
    const int qv = w_qmin + l15;                  // this lane's q row
    {
        const float* qp = q_q + bh_off + (size_t)(w_qmin + l15) * sstride;
        #pragma unroll
        for (int kc = 0; kc < 2; ++kc) {
            const int d0 = kc * 32 + l4 * 8;
            float4 a = *reinterpret_cast<const float4*>(qp + d0);
            float4 c = *reinterpret_cast<const float4*>(qp + d0 + 4);
            short8 f;
            f[0]=f2bf(a.x*c2); f[1]=f2bf(a.y*c2); f[2]=f2bf(a.z*c2); f[3]=f2bf(a.w*c2);
            f[4]=f2bf(c.x*c2); f[5]=f2bf(c.y*c2); f[6]=f2bf(c.z*c2); f[7]=f2bf(c.w*c2);
            qf[kc] = f;
        }
    }

    // O[db]: col=q=l15, row=d = db*16 + l4*4 + r
    f32x4 O[4] = {{0.f,0.f,0.f,0.f},{0.f,0.f,0.f,0.f},{0.f,0.f,0.f,0.f},{0.f,0.f,0.f,0.f}};
    float lsum = 0.f;                             // lane-partial sum for q=qv

    const int ntiles = qtile + 1;
    const size_t kg_bh = (size_t)bh * S_LEN * 128;
    const size_t vg_bh = (size_t)bh * NTILES * 8192;
    const int woff = w * 2048 + l * 16;

    auto STAGE = [&](int X, int t) {
        const char* ks   = Kg + kg_bh + (size_t)t * KVBLK * 128 + woff;
        const char* vsrc = Vg + vg_bh + (size_t)t * 8192 + woff;
        gl_lds16(ks,          &Kl[X][w * 2048]);
        gl_lds16(ks + 1024,   &Kl[X][w * 2048 + 1024]);
        gl_lds16(vsrc,        &Vl[X][w * 2048]);
        gl_lds16(vsrc + 1024, &Vl[X][w * 2048 + 1024]);
    };

    STAGE(0, 0);
    char* Pw = Pl + w * 2048 + l15 * 128;         // this lane's P row (q=qv)
    const int pswz = (l15 & 7) << 4;

    for (int t = 0; t < ntiles; ++t) {
        const int cur = t & 1;
        if (t + 1 < ntiles) {
            STAGE(cur ^ 1, t + 1);
            asm volatile("s_waitcnt vmcnt(4)" ::: "memory");
        } else {
            asm volatile("s_waitcnt vmcnt(0)" ::: "memory");
        }
        __builtin_amdgcn_s_barrier();

        // ---- QK^T (swapped): sc[cb] col=q=l15, row=kv_loc=l4*4+r ----
        f32x4 sc[4];
        #pragma unroll
        for (int cb = 0; cb < 4; ++cb) {
            f32x4 acc = {0.f, 0.f, 0.f, 0.f};
            #pragma unroll
            for (int kc = 0; kc < 2; ++kc) {
                const int row  = cb * 16 + l15;
                const int colb = kc * 64 + l4 * 16;
                short8 kf = *reinterpret_cast<const short8*>(
                    &Kl[cur][row * 128 + (colb ^ ((row & 7) << 4))]);
                acc = __builtin_amdgcn_mfma_f32_16x16x32_bf16(kf, qf[kc], acc, 0, 0, 0);
            }
            sc[cb] = acc;
        }

        // ---- static-max softmax, fully lane-local ----
        const bool needMask = (t == ntiles - 1);
        #pragma unroll
        for (int cb = 0; cb < 4; ++cb) {
            const int kvb = t * KVBLK + cb * 16 + l4 * 4;
            float e0, e1, e2, e3;
            float s0 = sc[cb][0], s1 = sc[cb][1], s2 = sc[cb][2], s3 = sc[cb][3];
            if (needMask) {
                if (kvb + 0 > qv) s0 = -1e30f;
                if (kvb + 1 > qv) s1 = -1e30f;
                if (kvb + 2 > qv) s2 = -1e30f;
                if (kvb + 3 > qv) s3 = -1e30f;
            }
            e0 = exp2f(s0 - MBIAS);
            e1 = exp2f(s1 - MBIAS);
            e2 = exp2f(s2 - MBIAS);
            e3 = exp2f(s3 - MBIAS);
            lsum += (e0 + e1) + (e2 + e3);
            short4v pk;
            pk[0] = f2bf(e0); pk[1] = f2bf(e1); pk[2] = f2bf(e2); pk[3] = f2bf(e3);
            *reinterpret_cast<short4v*>(&Pw[(cb * 32 + l4 * 8) ^ pswz]) = pk;
        }

        // ---- PV (swapped): O[db] += Vt_frag * P_frag ----
        #pragma unroll
        for (int kc = 0; kc < 2; ++kc) {
            short8 pb = *reinterpret_cast<const short8*>(
                &Pw[(kc * 64 + l4 * 16) ^ pswz]);
            #pragma unroll
            for (int db = 0; db < 4; ++db) {
                const int row  = db * 16 + l15;
                const int colb = kc * 64 + l4 * 16;
                short8 vf = *reinterpret_cast<const short8*>(
                    &Vl[cur][row * 128 + (colb ^ ((row & 7) << 4))]);
                O[db] = __builtin_amdgcn_mfma_f32_16x16x32_bf16(vf, pb, O[db], 0, 0, 0);
            }
        }

        asm volatile("s_waitcnt lgkmcnt(0)" ::: "memory");
        __builtin_amdgcn_s_barrier();
    }

    // ---- epilogue: reduce lsum across l4 groups, normalize, store ----
    lsum += __shfl_xor(lsum, 16);
    lsum += __shfl_xor(lsum, 32);
    const float inv = vs / lsum;
    float* op = out + bh_off + (size_t)qv * sstride;
    #pragma unroll
    for (int db = 0; db < 4; ++db) {
        float4 o;
        o.x = O[db][0] * inv; o.y = O[db][1] * inv;
        o.z = O[db][2] * inv; o.w = O[db][3] * inv;
        *reinterpret_cast<float4*>(op + db * 16 + l4 * 4) = o;
    }
}

// ---------------- fallback (round-1 kernel, used if ws too small) ---------
__global__ __launch_bounds__(256)
void fa_fwd_fallback(const float* __restrict__ q_q, const float* __restrict__ k_q,
                     const float* __restrict__ v_q, const float* __restrict__ q_scale,
                     const float* __restrict__ k_scale, const float* __restrict__ v_scale,
                     float* __restrict__ out)
{
    __shared__ char lds[8192 + 8192 + 4 * 16 * 144];
    char* Kl = lds;
    char* Vl = lds + 8192;
    char* Pl = lds + 16384;

    const int tid = threadIdx.x;
    const int w   = tid >> 6;
    const int l   = tid & 63;
    const int l15 = l & 15;
    const int l4  = l >> 4;

    const int qtile = (int)gridDim.x - 1 - (int)blockIdx.x;
    const int bh = blockIdx.y;
    const int b  = bh >> 4;
    const int h  = bh & 15;

    const int qbase = qtile * QBLK;
    const int sstride = HEADS * DIM;
    const size_t bh_off = ((size_t)b * S_LEN * HEADS + h) * DIM;

    const float c2 = q_scale[h] * k_scale[h] * 0.125f * 1.4426950408889634f;
    const float vs = v_scale[h];

    short8 qf[2];
    const int w_qmin = qbase + w * 16;
    {
        const float* qp = q_q + bh_off + (size_t)(w_qmin + l15) * sstride;
        #pragma unroll
        for (int kc = 0; kc < 2; ++kc) {
            const int d0 = kc * 32 + l4 * 8;
            float4 a = *reinterpret_cast<const float4*>(qp + d0);
            float4 c = *reinterpret_cast<const float4*>(qp + d0 + 4);
            short8 f;
            f[0]=f2bf(a.x*c2); f[1]=f2bf(a.y*c2); f[2]=f2bf(a.z*c2); f[3]=f2bf(a.w*c2);
            f[4]=f2bf(c.x*c2); f[5]=f2bf(c.y*c2); f[6]=f2bf(c.z*c2); f[7]=f2bf(c.w*c2);
            qf[kc] = f;
        }
    }

    f32x4 O[4] = {{0.f,0.f,0.f,0.f},{0.f,0.f,0.f,0.f},{0.f,0.f,0.f,0.f},{0.f,0.f,0.f,0.f}};
    float m2[4], lsum[4];
    #pragma unroll
    for (int r = 0; r < 4; ++r) { m2[r] = -1e30f; lsum[r] = 0.f; }

    const int kv_end = qbase + QBLK;

    for (int kvbase = 0; kvbase < kv_end; kvbase += KVBLK) {
        __syncthreads();
        {
            const float* kp = k_q + bh_off + (size_t)kvbase * sstride;
            #pragma unroll
            for (int i = 0; i < 4; ++i) {
                const int f4i = tid + i * 256;
                const int row  = f4i >> 4;
                const int col4 = (f4i & 15) * 4;
                float4 v = *reinterpret_cast<const float4*>(kp + (size_t)row * sstride + col4);
                uint2 pk;
                pk.x = (unsigned)(unsigned short)f2bf(v.x) | ((unsigned)(unsigned short)f2bf(v.y) << 16);
                pk.y = (unsigned)(unsigned short)f2bf(v.z) | ((unsigned)(unsigned short)f2bf(v.w) << 16);
                const int byte = row * 128 + ((col4 * 2) ^ ((row & 7) << 4));
                *reinterpret_cast<uint2*>(&Kl[byte]) = pk;
            }
        }
        {
            const float* vp = v_q + bh_off + (size_t)kvbase * sstride;
            #pragma unroll
            for (int g = 0; g < 2; ++g) {
                const int kv0 = w * 16 + g * 8;
                short8 f;
                #pragma unroll
                for (int j = 0; j < 8; ++j)
                    f[j] = f2bf(vp[(size_t)(kv0 + j) * sstride + l]);
                const int byte = l * 128 + ((kv0 * 2) ^ ((l & 7) << 4));
                *reinterpret_cast<short8*>(&Vl[byte]) = f;
            }
        }
        __syncthreads();

        const bool needMask = (kvbase + KVBLK - 1 > w_qmin);
        f32x4 sc[4];
        #pragma unroll
        for (int cb = 0; cb < 4; ++cb) {
            f32x4 acc = {0.f, 0.f, 0.f, 0.f};
            #pragma unroll
            for (int kc = 0; kc < 2; ++kc) {
                const int row  = cb * 16 + l15;
                const int colb = (kc * 32 + l4 * 8) * 2;
                short8 bf = *reinterpret_cast<const short8*>(
                    &Kl[row * 128 + (colb ^ ((row & 7) << 4))]);
                acc = __builtin_amdgcn_mfma_f32_16x16x32_bf16(qf[kc], bf, acc, 0, 0, 0);
            }
            sc[cb] = acc;
        }
        float p[4][4];
        #pragma unroll
        for (int cb = 0; cb < 4; ++cb) {
            const int kv = kvbase + cb * 16 + l15;
            #pragma unroll
            for (int r = 0; r < 4; ++r) {
                float s = sc[cb][r];
                if (needMask && kv > (w_qmin + l4 * 4 + r)) s = -1e30f;
                p[cb][r] = s;
            }
        }
        char* Pw = Pl + w * (16 * 144);
        #pragma unroll
        for (int r = 0; r < 4; ++r) {
            float t = fmaxf(fmaxf(p[0][r], p[1][r]), fmaxf(p[2][r], p[3][r]));
            t = fmaxf(t, __shfl_xor(t, 1));
            t = fmaxf(t, __shfl_xor(t, 2));
            t = fmaxf(t, __shfl_xor(t, 4));
            t = fmaxf(t, __shfl_xor(t, 8));
            const float mn   = fmaxf(m2[r], t);
            const float corr = exp2f(m2[r] - mn);
            m2[r] = mn;
            lsum[r] *= corr;
            #pragma unroll
            for (int db = 0; db < 4; ++db) O[db][r] *= corr;
            float ps = 0.f;
            #pragma unroll
            for (int cb = 0; cb < 4; ++cb) {
                const float e = exp2f(p[cb][r] - mn);
                p[cb][r] = e;
                ps += e;
            }
            lsum[r] += ps;
            const int prow = l4 * 4 + r;
            #pragma unroll
            for (int cb = 0; cb < 4; ++cb)
                *reinterpret_cast<short*>(&Pw[prow * 144 + (cb * 16 + l15) * 2]) =
                    f2bf(p[cb][r]);
        }
        #pragma unroll
        for (int kc = 0; kc < 2; ++kc) {
            short8 pf = *reinterpret_cast<const short8*>(
                &Pw[l15 * 144 + (kc * 32 + l4 * 8) * 2]);
            #pragma unroll
            for (int db = 0; db < 4; ++db) {
                const int row  = db * 16 + l15;
                const int colb = (kc * 32 + l4 * 8) * 2;
                short8 vf = *reinterpret_cast<const short8*>(
                    &Vl[row * 128 + (colb ^ ((row & 7) << 4))]);
                O[db] = __builtin_amdgcn_mfma_f32_16x16x32_bf16(pf, vf, O[db], 0, 0, 0);
            }
        }
    }

    #pragma unroll
    for (int r = 0; r < 4; ++r) {
        float t = lsum[r];
        t += __shfl_xor(t, 1);
        t += __shfl_xor(t, 2);
        t += __shfl_xor(t, 4);
        t += __shfl_xor(t, 8);
        const float inv = vs / t;
        const int q = w_qmin + l4 * 4 + r;
        float* op = out + bh_off + (size_t)q * sstride;
        #pragma unroll
        for (int db = 0; db < 4; ++db)
            op[db * 16 + l15] = O[db][r] * inv;
    }
}

extern "C" void kernel_launch(void* const* d_in, const int* in_sizes, int n_in,
                              void* d_out, int out_size, void* d_ws, size_t ws_size,
                              hipStream_t stream) {
    const float* q_q     = (const float*)d_in[0];
    const float* k_q     = (const float*)d_in[1];
    const float* v_q     = (const float*)d_in[2];
    const float* q_scale = (const float*)d_in[3];
    const float* k_scale = (const float*)d_in[4];
    const float* v_scale = (const float*)d_in[5];
    float* out = (float*)d_out;

    const size_t kbytes = (size_t)NBH * S_LEN * 128;   // 16.78 MB
    const size_t need   = kbytes * 2;

    if (ws_size >= need) {
        char* Kg = (char*)d_ws;
        char* Vg = Kg + kbytes;
        prep_k_kernel<<<dim3(4096), dim3(256), 0, stream>>>(k_q, Kg);
        prep_v_kernel<<<dim3(NTILES, NBH), dim3(256), 0, stream>>>(v_q, Vg);
        fa_fwd_pre<<<dim3(NTILES, NBH), dim3(256), 0, stream>>>(
            q_q, Kg, Vg, q_scale, k_scale, v_scale, out);
    } else {
        fa_fwd_fallback<<<dim3(NTILES, NBH), dim3(256), 0, stream>>>(
            q_q, k_q, v_q, q_scale, k_scale, v_scale, out);
    }
}